// Round 1
// baseline (717.854 us; speedup 1.0000x reference)
//
#include <hip/hip_runtime.h>
#include <math.h>

#define C1C 1e-4f       // 0.01^2
#define C2C 9e-4f       // 0.03^2
// Inputs: (32, 3, 512, 512) fp32; 8x8 patches of 64x64. plane = q*3 + c.
// Plane processed in two 32-col halves so LDS = 3*74*36*4 = 31968 B ->
// 5 blocks/CU (20 waves/CU) vs previous 3 (12 waves/CU). Buffers carry a
// 5-row zeroed halo top+bottom so vertical conv needs no clipping branches.

// Gaussian weights g[k] = exp(-(k-5)^2/4.5)/sum, precomputed in fp64.
#define GW0 0.00102838f
#define GW1 0.00759876f
#define GW2 0.03600077f
#define GW3 0.10936069f
#define GW4 0.21300554f
#define GW5 0.26601173f
__device__ __forceinline__ float conv11(const float* w) {
    // w points at first tap of an 11-wide window
    float a = GW0 * (w[0] + w[10]);
    a = fmaf(GW1, w[1] + w[9], a);
    a = fmaf(GW2, w[2] + w[8], a);
    a = fmaf(GW3, w[3] + w[7], a);
    a = fmaf(GW4, w[4] + w[6], a);
    a = fmaf(GW5, w[5], a);
    return a;
}

#define SROWS 74   // 5 halo + 64 data + 5 halo
#define SSTR  36   // 32 cols + 4 pad (16B-aligned rows, varies bank with row)

// ---------------------------------------------------------------------------
// Fused: per (patch q, channel c) plane: separable 11x11 gaussian convs over
// two 32-col halves, SSIM-map sum, MSE partials.
// grid (2048, 3), block 256. LDS = 31968 B -> 5 blocks/CU.
// ---------------------------------------------------------------------------
__global__ __launch_bounds__(256, 5) void ssim_fused_kernel(
    const float* __restrict__ A,  const float* __restrict__ Nimg,
    const float* __restrict__ GT, const float* __restrict__ G,
    const float* __restrict__ BG,
    float* __restrict__ ssim_sum, float* __restrict__ sa_sum,
    float* __restrict__ sbg_sum)
{
    __shared__ float S0[SROWS][SSTR];
    __shared__ float S1[SROWS][SSTR];
    __shared__ float S2[SROWS][SSTR];

    const int q  = blockIdx.x;          // patch 0..2047
    const int c  = blockIdx.y;          // channel 0..2
    const int b  = q >> 6;
    const int pp = q & 63;
    const int ph = pp >> 3;
    const int pw = pp & 7;
    const size_t base = ((size_t)(b * 3 + c) << 18)
                      + ((size_t)(ph * 64) << 9)
                      + (size_t)(pw * 64);
    const int t = threadIdx.x;

    // Zero the 5-row top/bottom halos of all three buffers (once).
    for (int i = t; i < 10 * SSTR; i += 256) {
        const int r  = i / SSTR;
        const int cc = i - r * SSTR;
        const int rr = (r < 5) ? r : 64 + r;        // rows 0..4, 69..73
        S0[rr][cc] = 0.f; S1[rr][cc] = 0.f; S2[rr][cc] = 0.f;
    }

    // Horizontal mapping: thread -> (row hr 0..63, 8-col segment hseg 0..3)
    const int hr   = t >> 2;
    const int hseg = t & 3;
    const int c0   = hseg << 3;               // local col in half: 0,8,16,24
    const size_t rowBase = base + ((size_t)hr << 9);
    // Vertical mapping: thread -> (col vcol 0..31, 8-row stripe)
    const int vcol = t & 31;
    const int vr0  = (t >> 5) << 3;           // padded window start row

    float accS = 0.f;

    for (int h = 0; h < 2; ++h) {
        const int g0 = (h << 5) + c0;         // global col of first output
        // ---------------- Horizontal pass (one half) -----------------------
        float xw[24], yw[24];
        #pragma unroll
        for (int m = 0; m < 6; ++m) {
            const int cb = g0 - 8 + 4 * m;    // global col of this float4
            float4 xv = make_float4(0.f, 0.f, 0.f, 0.f);
            float4 yv = make_float4(0.f, 0.f, 0.f, 0.f);
            if (cb >= 0 && cb < 64) {         // zero pad outside patch
                xv = *(const float4*)(Nimg + rowBase + cb);
                yv = *(const float4*)(GT   + rowBase + cb);
            }
            xw[4*m+0] = xv.x; xw[4*m+1] = xv.y; xw[4*m+2] = xv.z; xw[4*m+3] = xv.w;
            yw[4*m+0] = yv.x; yw[4*m+1] = yv.y; yw[4*m+2] = yv.z; yw[4*m+3] = yv.w;
        }

        float hx[8], hy[8];
        {
            float tp[24];
            #pragma unroll
            for (int i = 0; i < 24; ++i) tp[i] = xw[i] * yw[i];   // x*y
            #pragma unroll
            for (int mm = 0; mm < 2; ++mm) {
                float4 o;
                #pragma unroll
                for (int u = 0; u < 4; ++u) (&o.x)[u] = conv11(&tp[4*mm + u + 3]);
                *(float4*)&S2[5 + hr][c0 + 4*mm] = o;
            }
            #pragma unroll
            for (int i = 0; i < 24; ++i) tp[i] = xw[i] * xw[i];   // x^2
            #pragma unroll
            for (int mm = 0; mm < 2; ++mm) {
                float4 o;
                #pragma unroll
                for (int u = 0; u < 4; ++u) (&o.x)[u] = conv11(&tp[4*mm + u + 3]);
                *(float4*)&S0[5 + hr][c0 + 4*mm] = o;
            }
            #pragma unroll
            for (int i = 0; i < 24; ++i) tp[i] = yw[i] * yw[i];   // y^2
            #pragma unroll
            for (int mm = 0; mm < 2; ++mm) {
                float4 o;
                #pragma unroll
                for (int u = 0; u < 4; ++u) (&o.x)[u] = conv11(&tp[4*mm + u + 3]);
                *(float4*)&S1[5 + hr][c0 + 4*mm] = o;
            }
            #pragma unroll
            for (int o = 0; o < 8; ++o) hx[o] = conv11(&xw[o + 3]);
            #pragma unroll
            for (int o = 0; o < 8; ++o) hy[o] = conv11(&yw[o + 3]);
        }
        __syncthreads();

        // ---------------- Vertical round 1: Exx, Eyy, Exy ------------------
        float Exx[8], Eyy[8], Exy[8];
        {
            float w[18];
            #pragma unroll
            for (int d = 0; d < 18; ++d) w[d] = S0[vr0 + d][vcol];
            #pragma unroll
            for (int o = 0; o < 8; ++o) Exx[o] = conv11(&w[o]);
            #pragma unroll
            for (int d = 0; d < 18; ++d) w[d] = S1[vr0 + d][vcol];
            #pragma unroll
            for (int o = 0; o < 8; ++o) Eyy[o] = conv11(&w[o]);
            #pragma unroll
            for (int d = 0; d < 18; ++d) w[d] = S2[vr0 + d][vcol];
            #pragma unroll
            for (int o = 0; o < 8; ++o) Exy[o] = conv11(&w[o]);
        }
        __syncthreads();

        // ---------------- Write hx, hy (kept in regs) ----------------------
        #pragma unroll
        for (int mm = 0; mm < 2; ++mm) {
            float4 o0, o1;
            #pragma unroll
            for (int u = 0; u < 4; ++u) {
                (&o0.x)[u] = hx[4*mm + u];
                (&o1.x)[u] = hy[4*mm + u];
            }
            *(float4*)&S0[5 + hr][c0 + 4*mm] = o0;
            *(float4*)&S1[5 + hr][c0 + 4*mm] = o1;
        }
        __syncthreads();

        // ---------------- Vertical round 2 + SSIM combine ------------------
        {
            float w[18];
            #pragma unroll
            for (int d = 0; d < 18; ++d) w[d] = S0[vr0 + d][vcol];
            float mu1[8];
            #pragma unroll
            for (int o = 0; o < 8; ++o) mu1[o] = conv11(&w[o]);
            #pragma unroll
            for (int d = 0; d < 18; ++d) w[d] = S1[vr0 + d][vcol];
            #pragma unroll
            for (int o = 0; o < 8; ++o) {
                const float m2  = conv11(&w[o]);
                const float m1  = mu1[o];
                const float m1s = m1 * m1, m2s = m2 * m2, m12 = m1 * m2;
                const float s1  = Exx[o] - m1s;
                const float s2v = Eyy[o] - m2s;
                const float s12 = Exy[o] - m12;
                const float num = (2.f * m12 + C1C) * (2.f * s12 + C2C);
                const float den = (m1s + m2s + C1C) * (s1 + s2v + C2C);
                accS += num / den;
            }
        }
        __syncthreads();      // buffers free for next half (or reduction)
    }

    // ---------------- Fused MSE partials over this plane -------------------
    float sa = 0.f, sbg = 0.f;
    #pragma unroll
    for (int it = 0; it < 4; ++it) {
        const int idx  = t + 256 * it;        // 0..1023 float4 slots
        const int row  = idx >> 4;
        const int col4 = (idx & 15) << 2;
        const size_t off = base + ((size_t)row << 9) + col4;
        const float4 av  = *(const float4*)(A  + off);
        const float4 gv  = *(const float4*)(G  + off);
        const float4 bgv = *(const float4*)(BG + off);
        float d0 = bgv.x - gv.x, d1 = bgv.y - gv.y, d2 = bgv.z - gv.z, d3 = bgv.w - gv.w;
        sbg += d0*d0 + d1*d1 + d2*d2 + d3*d3;
        float e0 = av.x - gv.x, e1 = av.y - gv.y, e2 = av.z - gv.z, e3 = av.w - gv.w;
        sa  += e0*e0 + e1*e1 + e2*e2 + e3*e3;
    }

    // ---------------- Block reduction of (accS, sa, sbg) -------------------
    #pragma unroll
    for (int off = 32; off; off >>= 1) {
        accS += __shfl_down(accS, off, 64);
        sa   += __shfl_down(sa,   off, 64);
        sbg  += __shfl_down(sbg,  off, 64);
    }
    const int wv = t >> 6;
    if ((t & 63) == 0) {
        S0[0][wv] = accS; S0[1][wv] = sa; S0[2][wv] = sbg;
    }
    __syncthreads();
    if (t == 0) {
        const int plane = q * 3 + c;
        ssim_sum[plane] = S0[0][0] + S0[0][1] + S0[0][2] + S0[0][3];
        sa_sum[plane]   = S0[1][0] + S0[1][1] + S0[1][2] + S0[1][3];
        sbg_sum[plane]  = S0[2][0] + S0[2][1] + S0[2][2] + S0[2][3];
    }
}

// ---------------------------------------------------------------------------
// Final combine: 1 block, 256 threads, no atomics, deterministic.
// ---------------------------------------------------------------------------
__global__ __launch_bounds__(256) void combine_kernel(
    const float* __restrict__ ssim_sum, const float* __restrict__ sa_sum,
    const float* __restrict__ sbg_sum, float* __restrict__ out)
{
    __shared__ float red[4];
    const int t = threadIdx.x;
    const float invN = 1.f / 12288.f;     // 3*64*64
    float acc = 0.f;
    #pragma unroll
    for (int r = 0; r < 8; ++r) {
        const int qq = t + 256 * r;       // patch 0..2047
        const float ss = ssim_sum[3*qq] + ssim_sum[3*qq+1] + ssim_sum[3*qq+2];
        const float sa = sa_sum[3*qq]   + sa_sum[3*qq+1]   + sa_sum[3*qq+2];
        const float sb = sbg_sum[3*qq]  + sbg_sum[3*qq+1]  + sbg_sum[3*qq+2];
        const float ssim = ss * invN;
        const float diff = fminf(1.f - ssim, 1.f);     // LD = 1.0
        acc += diff * (sb * invN) + (1.f - diff) * (sa * invN);
    }
    #pragma unroll
    for (int off = 32; off; off >>= 1) acc += __shfl_down(acc, off, 64);
    if ((t & 63) == 0) red[t >> 6] = acc;
    __syncthreads();
    if (t == 0) out[0] = red[0] + red[1] + red[2] + red[3];
}

extern "C" void kernel_launch(void* const* d_in, const int* in_sizes, int n_in,
                              void* d_out, int out_size, void* d_ws, size_t ws_size,
                              hipStream_t stream) {
    const float* A  = (const float*)d_in[0];
    const float* Nn = (const float*)d_in[1];
    const float* GT = (const float*)d_in[2];
    const float* G  = (const float*)d_in[3];
    const float* BG = (const float*)d_in[4];
    float* out      = (float*)d_out;

    float* ssim_sum = (float*)d_ws;            // 6144 floats
    float* sa_sum   = ssim_sum + 6144;         // 6144 floats
    float* sbg_sum  = ssim_sum + 12288;        // 6144 floats

    ssim_fused_kernel<<<dim3(2048, 3), 256, 0, stream>>>(
        A, Nn, GT, G, BG, ssim_sum, sa_sum, sbg_sum);
    combine_kernel<<<1, 256, 0, stream>>>(ssim_sum, sa_sum, sbg_sum, out);
}

// Round 2
// 536.393 us; speedup vs baseline: 1.3383x; 1.3383x over previous
//
#include <hip/hip_runtime.h>
#include <math.h>

#define C1C 1e-4f       // 0.01^2
#define C2C 9e-4f       // 0.03^2
// Inputs: (32, 3, 512, 512) fp32; 8x8 patches of 64x64. plane = q*3 + c.
// Plane processed in two 32-col halves so LDS = 3*74*36*4 = 31968 B ->
// up to 5 blocks/CU by LDS. Buffers carry a 5-row zeroed halo top+bottom so
// vertical conv is branch-free.
// __launch_bounds__(256,4): cap 128 VGPR. (256,5) capped at ~102 and caused
// a spill cascade (VGPR 48, +830 MB scratch reads AND writes, VALUBusy 20%).

// Gaussian weights g[k] = exp(-(k-5)^2/4.5)/sum, precomputed in fp64.
#define GW0 0.00102838f
#define GW1 0.00759876f
#define GW2 0.03600077f
#define GW3 0.10936069f
#define GW4 0.21300554f
#define GW5 0.26601173f
__device__ __forceinline__ float conv11(const float* w) {
    // w points at first tap of an 11-wide window
    float a = GW0 * (w[0] + w[10]);
    a = fmaf(GW1, w[1] + w[9], a);
    a = fmaf(GW2, w[2] + w[8], a);
    a = fmaf(GW3, w[3] + w[7], a);
    a = fmaf(GW4, w[4] + w[6], a);
    a = fmaf(GW5, w[5], a);
    return a;
}

#define SROWS 74   // 5 halo + 64 data + 5 halo
#define SSTR  36   // 32 cols + 4 pad (16B-aligned rows; +36 per row shifts
                   // bank by 4, and the 8-row stripe offset 8*36=288 ≡ 0
                   // mod 32 -> half-waves alias 2-way = free)

// ---------------------------------------------------------------------------
// Fused: per (patch q, channel c) plane: separable 11x11 gaussian convs over
// two 32-col halves, SSIM-map sum, MSE partials.
// grid (2048, 3), block 256. LDS = 31968 B.
// ---------------------------------------------------------------------------
__global__ __launch_bounds__(256, 4) void ssim_fused_kernel(
    const float* __restrict__ A,  const float* __restrict__ Nimg,
    const float* __restrict__ GT, const float* __restrict__ G,
    const float* __restrict__ BG,
    float* __restrict__ ssim_sum, float* __restrict__ sa_sum,
    float* __restrict__ sbg_sum)
{
    __shared__ float S0[SROWS][SSTR];
    __shared__ float S1[SROWS][SSTR];
    __shared__ float S2[SROWS][SSTR];

    const int q  = blockIdx.x;          // patch 0..2047
    const int c  = blockIdx.y;          // channel 0..2
    const int b  = q >> 6;
    const int pp = q & 63;
    const int ph = pp >> 3;
    const int pw = pp & 7;
    const size_t base = ((size_t)(b * 3 + c) << 18)
                      + ((size_t)(ph * 64) << 9)
                      + (size_t)(pw * 64);
    const int t = threadIdx.x;

    // Zero the 5-row top/bottom halos of all three buffers (once; V-pass
    // never writes LDS and H-pass writes only rows 5..68, so halos persist).
    for (int i = t; i < 10 * SSTR; i += 256) {
        const int r  = i / SSTR;
        const int cc = i - r * SSTR;
        const int rr = (r < 5) ? r : 64 + r;        // rows 0..4, 69..73
        S0[rr][cc] = 0.f; S1[rr][cc] = 0.f; S2[rr][cc] = 0.f;
    }

    // Horizontal mapping: thread -> (row hr 0..63, 8-col segment hseg 0..3)
    const int hr   = t >> 2;
    const int hseg = t & 3;
    const int c0   = hseg << 3;               // local col in half: 0,8,16,24
    const size_t rowBase = base + ((size_t)hr << 9);
    // Vertical mapping: thread -> (col vcol 0..31, 8-row stripe)
    const int vcol = t & 31;
    const int vr0  = (t >> 5) << 3;           // padded window start row

    float accS = 0.f;

    for (int h = 0; h < 2; ++h) {
        const int g0 = (h << 5) + c0;         // global col of first output
        // ---------------- Horizontal pass (one half) -----------------------
        // Window covers global cols g0-8 .. g0+15 (24 floats); outputs use
        // taps at window idx 3..20 only (float4 alignment loads the rest).
        float xw[24], yw[24];
        #pragma unroll
        for (int m = 0; m < 6; ++m) {
            const int cb = g0 - 8 + 4 * m;    // global col of this float4
            float4 xv = make_float4(0.f, 0.f, 0.f, 0.f);
            float4 yv = make_float4(0.f, 0.f, 0.f, 0.f);
            if (cb >= 0 && cb < 64) {         // zero pad outside patch
                xv = *(const float4*)(Nimg + rowBase + cb);
                yv = *(const float4*)(GT   + rowBase + cb);
            }
            xw[4*m+0] = xv.x; xw[4*m+1] = xv.y; xw[4*m+2] = xv.z; xw[4*m+3] = xv.w;
            yw[4*m+0] = yv.x; yw[4*m+1] = yv.y; yw[4*m+2] = yv.z; yw[4*m+3] = yv.w;
        }

        float hx[8], hy[8];
        {
            // p[j] = product at window index j+3 (only taps 3..20 are used);
            // output u reads p[u..u+10].
            float p[18];
            #pragma unroll
            for (int i = 0; i < 18; ++i) p[i] = xw[i + 3] * yw[i + 3]; // x*y
            #pragma unroll
            for (int mm = 0; mm < 2; ++mm) {
                float4 o;
                #pragma unroll
                for (int u = 0; u < 4; ++u) (&o.x)[u] = conv11(&p[4*mm + u]);
                *(float4*)&S2[5 + hr][c0 + 4*mm] = o;
            }
            #pragma unroll
            for (int i = 0; i < 18; ++i) p[i] = xw[i + 3] * xw[i + 3]; // x^2
            #pragma unroll
            for (int mm = 0; mm < 2; ++mm) {
                float4 o;
                #pragma unroll
                for (int u = 0; u < 4; ++u) (&o.x)[u] = conv11(&p[4*mm + u]);
                *(float4*)&S0[5 + hr][c0 + 4*mm] = o;
            }
            #pragma unroll
            for (int i = 0; i < 18; ++i) p[i] = yw[i + 3] * yw[i + 3]; // y^2
            #pragma unroll
            for (int mm = 0; mm < 2; ++mm) {
                float4 o;
                #pragma unroll
                for (int u = 0; u < 4; ++u) (&o.x)[u] = conv11(&p[4*mm + u]);
                *(float4*)&S1[5 + hr][c0 + 4*mm] = o;
            }
            #pragma unroll
            for (int o = 0; o < 8; ++o) hx[o] = conv11(&xw[o + 3]);
            #pragma unroll
            for (int o = 0; o < 8; ++o) hy[o] = conv11(&yw[o + 3]);
        }
        __syncthreads();

        // ---------------- Vertical round 1: Exx, Eyy, Exy ------------------
        float Exx[8], Eyy[8], Exy[8];
        {
            float w[18];
            #pragma unroll
            for (int d = 0; d < 18; ++d) w[d] = S0[vr0 + d][vcol];
            #pragma unroll
            for (int o = 0; o < 8; ++o) Exx[o] = conv11(&w[o]);
            #pragma unroll
            for (int d = 0; d < 18; ++d) w[d] = S1[vr0 + d][vcol];
            #pragma unroll
            for (int o = 0; o < 8; ++o) Eyy[o] = conv11(&w[o]);
            #pragma unroll
            for (int d = 0; d < 18; ++d) w[d] = S2[vr0 + d][vcol];
            #pragma unroll
            for (int o = 0; o < 8; ++o) Exy[o] = conv11(&w[o]);
        }
        __syncthreads();

        // ---------------- Write hx, hy (kept in regs) ----------------------
        #pragma unroll
        for (int mm = 0; mm < 2; ++mm) {
            float4 o0, o1;
            #pragma unroll
            for (int u = 0; u < 4; ++u) {
                (&o0.x)[u] = hx[4*mm + u];
                (&o1.x)[u] = hy[4*mm + u];
            }
            *(float4*)&S0[5 + hr][c0 + 4*mm] = o0;
            *(float4*)&S1[5 + hr][c0 + 4*mm] = o1;
        }
        __syncthreads();

        // ---------------- Vertical round 2 + SSIM combine ------------------
        {
            float w[18];
            #pragma unroll
            for (int d = 0; d < 18; ++d) w[d] = S0[vr0 + d][vcol];
            float mu1[8];
            #pragma unroll
            for (int o = 0; o < 8; ++o) mu1[o] = conv11(&w[o]);
            #pragma unroll
            for (int d = 0; d < 18; ++d) w[d] = S1[vr0 + d][vcol];
            #pragma unroll
            for (int o = 0; o < 8; ++o) {
                const float m2  = conv11(&w[o]);
                const float m1  = mu1[o];
                const float m1s = m1 * m1, m2s = m2 * m2, m12 = m1 * m2;
                const float s1  = Exx[o] - m1s;
                const float s2v = Eyy[o] - m2s;
                const float s12 = Exy[o] - m12;
                const float num = (2.f * m12 + C1C) * (2.f * s12 + C2C);
                const float den = (m1s + m2s + C1C) * (s1 + s2v + C2C);
                accS += num / den;
            }
        }
        __syncthreads();      // buffers free for next half (or reduction)
    }

    // ---------------- Fused MSE partials over this plane -------------------
    float sa = 0.f, sbg = 0.f;
    #pragma unroll
    for (int it = 0; it < 4; ++it) {
        const int idx  = t + 256 * it;        // 0..1023 float4 slots
        const int row  = idx >> 4;
        const int col4 = (idx & 15) << 2;
        const size_t off = base + ((size_t)row << 9) + col4;
        const float4 av  = *(const float4*)(A  + off);
        const float4 gv  = *(const float4*)(G  + off);
        const float4 bgv = *(const float4*)(BG + off);
        float d0 = bgv.x - gv.x, d1 = bgv.y - gv.y, d2 = bgv.z - gv.z, d3 = bgv.w - gv.w;
        sbg += d0*d0 + d1*d1 + d2*d2 + d3*d3;
        float e0 = av.x - gv.x, e1 = av.y - gv.y, e2 = av.z - gv.z, e3 = av.w - gv.w;
        sa  += e0*e0 + e1*e1 + e2*e2 + e3*e3;
    }

    // ---------------- Block reduction of (accS, sa, sbg) -------------------
    #pragma unroll
    for (int off = 32; off; off >>= 1) {
        accS += __shfl_down(accS, off, 64);
        sa   += __shfl_down(sa,   off, 64);
        sbg  += __shfl_down(sbg,  off, 64);
    }
    const int wv = t >> 6;
    if ((t & 63) == 0) {
        S0[0][wv] = accS; S0[1][wv] = sa; S0[2][wv] = sbg;
    }
    __syncthreads();
    if (t == 0) {
        const int plane = q * 3 + c;
        ssim_sum[plane] = S0[0][0] + S0[0][1] + S0[0][2] + S0[0][3];
        sa_sum[plane]   = S0[1][0] + S0[1][1] + S0[1][2] + S0[1][3];
        sbg_sum[plane]  = S0[2][0] + S0[2][1] + S0[2][2] + S0[2][3];
    }
}

// ---------------------------------------------------------------------------
// Final combine: 1 block, 256 threads, no atomics, deterministic.
// ---------------------------------------------------------------------------
__global__ __launch_bounds__(256) void combine_kernel(
    const float* __restrict__ ssim_sum, const float* __restrict__ sa_sum,
    const float* __restrict__ sbg_sum, float* __restrict__ out)
{
    __shared__ float red[4];
    const int t = threadIdx.x;
    const float invN = 1.f / 12288.f;     // 3*64*64
    float acc = 0.f;
    #pragma unroll
    for (int r = 0; r < 8; ++r) {
        const int qq = t + 256 * r;       // patch 0..2047
        const float ss = ssim_sum[3*qq] + ssim_sum[3*qq+1] + ssim_sum[3*qq+2];
        const float sa = sa_sum[3*qq]   + sa_sum[3*qq+1]   + sa_sum[3*qq+2];
        const float sb = sbg_sum[3*qq]  + sbg_sum[3*qq+1]  + sbg_sum[3*qq+2];
        const float ssim = ss * invN;
        const float diff = fminf(1.f - ssim, 1.f);     // LD = 1.0
        acc += diff * (sb * invN) + (1.f - diff) * (sa * invN);
    }
    #pragma unroll
    for (int off = 32; off; off >>= 1) acc += __shfl_down(acc, off, 64);
    if ((t & 63) == 0) red[t >> 6] = acc;
    __syncthreads();
    if (t == 0) out[0] = red[0] + red[1] + red[2] + red[3];
}

extern "C" void kernel_launch(void* const* d_in, const int* in_sizes, int n_in,
                              void* d_out, int out_size, void* d_ws, size_t ws_size,
                              hipStream_t stream) {
    const float* A  = (const float*)d_in[0];
    const float* Nn = (const float*)d_in[1];
    const float* GT = (const float*)d_in[2];
    const float* G  = (const float*)d_in[3];
    const float* BG = (const float*)d_in[4];
    float* out      = (float*)d_out;

    float* ssim_sum = (float*)d_ws;            // 6144 floats
    float* sa_sum   = ssim_sum + 6144;         // 6144 floats
    float* sbg_sum  = ssim_sum + 12288;        // 6144 floats

    ssim_fused_kernel<<<dim3(2048, 3), 256, 0, stream>>>(
        A, Nn, GT, G, BG, ssim_sum, sa_sum, sbg_sum);
    combine_kernel<<<1, 256, 0, stream>>>(ssim_sum, sa_sum, sbg_sum, out);
}

// Round 3
// 445.296 us; speedup vs baseline: 1.6121x; 1.2046x over previous
//
#include <hip/hip_runtime.h>
#include <math.h>

#define C1C 1e-4f       // 0.01^2
#define C2C 9e-4f       // 0.03^2
// Inputs: (32, 3, 512, 512) fp32; 8x8 patches of 64x64. plane = q*3 + c.
// Plane processed in two 32-col halves so LDS = 3*74*36*4 = 31968 B ->
// up to 5 blocks/CU by LDS. Buffers carry a 5-row zeroed halo top+bottom so
// vertical conv is branch-free.
// REGISTER CAP HISTORY (do not tighten): (256,5) -> compiler chose 48 VGPR +
// 830 MB scratch each way; (256,4) -> chose 64 + 220 MB scratch. With a
// loose cap (256,3) the allocator picks the natural ~70-90 and never spills.
// Occupancy comes from the LDS budget, not from the launch bound.

// Gaussian weights g[k] = exp(-(k-5)^2/4.5)/sum, precomputed in fp64.
#define GW0 0.00102838f
#define GW1 0.00759876f
#define GW2 0.03600077f
#define GW3 0.10936069f
#define GW4 0.21300554f
#define GW5 0.26601173f
__device__ __forceinline__ float conv11(const float* w) {
    // w points at first tap of an 11-wide window
    float a = GW0 * (w[0] + w[10]);
    a = fmaf(GW1, w[1] + w[9], a);
    a = fmaf(GW2, w[2] + w[8], a);
    a = fmaf(GW3, w[3] + w[7], a);
    a = fmaf(GW4, w[4] + w[6], a);
    a = fmaf(GW5, w[5], a);
    return a;
}

#define SROWS 74   // 5 halo + 64 data + 5 halo
#define SSTR  36   // 32 cols + 4 pad (16B-aligned rows; +36 per row shifts
                   // bank by 4; 8-row stripe offset 8*36=288 ≡ 0 mod 32 ->
                   // half-waves alias 2-way = free)

// ---------------------------------------------------------------------------
// Fused: per (patch q, channel c) plane: separable 11x11 gaussian convs over
// two 32-col halves, SSIM-map sum, MSE partials.
// grid (2048, 3), block 256. LDS = 31968 B.
// ---------------------------------------------------------------------------
__global__ __launch_bounds__(256, 3) void ssim_fused_kernel(
    const float* __restrict__ A,  const float* __restrict__ Nimg,
    const float* __restrict__ GT, const float* __restrict__ G,
    const float* __restrict__ BG,
    float* __restrict__ ssim_sum, float* __restrict__ sa_sum,
    float* __restrict__ sbg_sum)
{
    __shared__ float S0[SROWS][SSTR];
    __shared__ float S1[SROWS][SSTR];
    __shared__ float S2[SROWS][SSTR];

    const int q  = blockIdx.x;          // patch 0..2047
    const int c  = blockIdx.y;          // channel 0..2
    const int b  = q >> 6;
    const int pp = q & 63;
    const int ph = pp >> 3;
    const int pw = pp & 7;
    const size_t base = ((size_t)(b * 3 + c) << 18)
                      + ((size_t)(ph * 64) << 9)
                      + (size_t)(pw * 64);
    const int t = threadIdx.x;

    // Zero the 5-row top/bottom halos of all three buffers (once; V-pass
    // never writes LDS and H-pass writes only rows 5..68, so halos persist).
    for (int i = t; i < 10 * SSTR; i += 256) {
        const int r  = i / SSTR;
        const int cc = i - r * SSTR;
        const int rr = (r < 5) ? r : 64 + r;        // rows 0..4, 69..73
        S0[rr][cc] = 0.f; S1[rr][cc] = 0.f; S2[rr][cc] = 0.f;
    }

    // Horizontal mapping: thread -> (row hr 0..63, 8-col segment hseg 0..3)
    const int hr   = t >> 2;
    const int hseg = t & 3;
    const int c0   = hseg << 3;               // local col in half: 0,8,16,24
    const size_t rowBase = base + ((size_t)hr << 9);
    // Vertical mapping: thread -> (col vcol 0..31, 8-row stripe)
    const int vcol = t & 31;
    const int vr0  = (t >> 5) << 3;           // padded window start row

    float accS = 0.f;

    for (int h = 0; h < 2; ++h) {
        const int g0 = (h << 5) + c0;         // global col of first output
        // ---------------- Horizontal pass (one half) -----------------------
        // Only window taps for global cols g0-5 .. g0+12 (18 floats) are ever
        // referenced; the float4 loads cover g0-8 .. g0+15, extra lanes
        // discarded at compile time. xs[j] = image col g0-5+j.
        float xs[18], ys[18];
        #pragma unroll
        for (int m = 0; m < 6; ++m) {
            const int cb = g0 - 8 + 4 * m;    // global col of this float4
            float4 xv = make_float4(0.f, 0.f, 0.f, 0.f);
            float4 yv = make_float4(0.f, 0.f, 0.f, 0.f);
            if (cb >= 0 && cb < 64) {         // never straddles the boundary
                xv = *(const float4*)(Nimg + rowBase + cb);
                yv = *(const float4*)(GT   + rowBase + cb);
            }
            #pragma unroll
            for (int u = 0; u < 4; ++u) {
                const int j = 4 * m + u - 3;  // xs index
                if (j >= 0 && j < 18) {
                    xs[j] = (&xv.x)[u];
                    ys[j] = (&yv.x)[u];
                }
            }
        }

        float hx[8], hy[8];
        {
            // p[i] = product at xs index i; output u reads p[u..u+10].
            float p[18];
            #pragma unroll
            for (int i = 0; i < 18; ++i) p[i] = xs[i] * ys[i];   // x*y
            #pragma unroll
            for (int mm = 0; mm < 2; ++mm) {
                float4 o;
                #pragma unroll
                for (int u = 0; u < 4; ++u) (&o.x)[u] = conv11(&p[4*mm + u]);
                *(float4*)&S2[5 + hr][c0 + 4*mm] = o;
            }
            #pragma unroll
            for (int i = 0; i < 18; ++i) p[i] = xs[i] * xs[i];   // x^2
            #pragma unroll
            for (int mm = 0; mm < 2; ++mm) {
                float4 o;
                #pragma unroll
                for (int u = 0; u < 4; ++u) (&o.x)[u] = conv11(&p[4*mm + u]);
                *(float4*)&S0[5 + hr][c0 + 4*mm] = o;
            }
            #pragma unroll
            for (int i = 0; i < 18; ++i) p[i] = ys[i] * ys[i];   // y^2
            #pragma unroll
            for (int mm = 0; mm < 2; ++mm) {
                float4 o;
                #pragma unroll
                for (int u = 0; u < 4; ++u) (&o.x)[u] = conv11(&p[4*mm + u]);
                *(float4*)&S1[5 + hr][c0 + 4*mm] = o;
            }
            #pragma unroll
            for (int o = 0; o < 8; ++o) hx[o] = conv11(&xs[o]);
            #pragma unroll
            for (int o = 0; o < 8; ++o) hy[o] = conv11(&ys[o]);
        }
        __syncthreads();

        // ---------------- Vertical round 1: Exx, Eyy, Exy ------------------
        float Exx[8], Eyy[8], Exy[8];
        {
            float w[18];
            #pragma unroll
            for (int d = 0; d < 18; ++d) w[d] = S0[vr0 + d][vcol];
            #pragma unroll
            for (int o = 0; o < 8; ++o) Exx[o] = conv11(&w[o]);
            #pragma unroll
            for (int d = 0; d < 18; ++d) w[d] = S1[vr0 + d][vcol];
            #pragma unroll
            for (int o = 0; o < 8; ++o) Eyy[o] = conv11(&w[o]);
            #pragma unroll
            for (int d = 0; d < 18; ++d) w[d] = S2[vr0 + d][vcol];
            #pragma unroll
            for (int o = 0; o < 8; ++o) Exy[o] = conv11(&w[o]);
        }
        __syncthreads();

        // ---------------- Write hx, hy (kept in regs) ----------------------
        #pragma unroll
        for (int mm = 0; mm < 2; ++mm) {
            float4 o0, o1;
            #pragma unroll
            for (int u = 0; u < 4; ++u) {
                (&o0.x)[u] = hx[4*mm + u];
                (&o1.x)[u] = hy[4*mm + u];
            }
            *(float4*)&S0[5 + hr][c0 + 4*mm] = o0;
            *(float4*)&S1[5 + hr][c0 + 4*mm] = o1;
        }
        __syncthreads();

        // ---------------- Vertical round 2 + SSIM combine ------------------
        {
            float w[18];
            #pragma unroll
            for (int d = 0; d < 18; ++d) w[d] = S0[vr0 + d][vcol];
            float mu1[8];
            #pragma unroll
            for (int o = 0; o < 8; ++o) mu1[o] = conv11(&w[o]);
            #pragma unroll
            for (int d = 0; d < 18; ++d) w[d] = S1[vr0 + d][vcol];
            #pragma unroll
            for (int o = 0; o < 8; ++o) {
                const float m2  = conv11(&w[o]);
                const float m1  = mu1[o];
                const float m1s = m1 * m1, m2s = m2 * m2, m12 = m1 * m2;
                const float s1  = Exx[o] - m1s;
                const float s2v = Eyy[o] - m2s;
                const float s12 = Exy[o] - m12;
                const float num = (2.f * m12 + C1C) * (2.f * s12 + C2C);
                const float den = (m1s + m2s + C1C) * (s1 + s2v + C2C);
                accS += num / den;
            }
        }
        __syncthreads();      // buffers free for next half (or reduction)
    }

    // ---------------- Fused MSE partials over this plane -------------------
    float sa = 0.f, sbg = 0.f;
    #pragma unroll
    for (int it = 0; it < 4; ++it) {
        const int idx  = t + 256 * it;        // 0..1023 float4 slots
        const int row  = idx >> 4;
        const int col4 = (idx & 15) << 2;
        const size_t off = base + ((size_t)row << 9) + col4;
        const float4 av  = *(const float4*)(A  + off);
        const float4 gv  = *(const float4*)(G  + off);
        const float4 bgv = *(const float4*)(BG + off);
        float d0 = bgv.x - gv.x, d1 = bgv.y - gv.y, d2 = bgv.z - gv.z, d3 = bgv.w - gv.w;
        sbg += d0*d0 + d1*d1 + d2*d2 + d3*d3;
        float e0 = av.x - gv.x, e1 = av.y - gv.y, e2 = av.z - gv.z, e3 = av.w - gv.w;
        sa  += e0*e0 + e1*e1 + e2*e2 + e3*e3;
    }

    // ---------------- Block reduction of (accS, sa, sbg) -------------------
    #pragma unroll
    for (int off = 32; off; off >>= 1) {
        accS += __shfl_down(accS, off, 64);
        sa   += __shfl_down(sa,   off, 64);
        sbg  += __shfl_down(sbg,  off, 64);
    }
    const int wv = t >> 6;
    if ((t & 63) == 0) {
        S0[0][wv] = accS; S0[1][wv] = sa; S0[2][wv] = sbg;
    }
    __syncthreads();
    if (t == 0) {
        const int plane = q * 3 + c;
        ssim_sum[plane] = S0[0][0] + S0[0][1] + S0[0][2] + S0[0][3];
        sa_sum[plane]   = S0[1][0] + S0[1][1] + S0[1][2] + S0[1][3];
        sbg_sum[plane]  = S0[2][0] + S0[2][1] + S0[2][2] + S0[2][3];
    }
}

// ---------------------------------------------------------------------------
// Final combine: 1 block, 256 threads, no atomics, deterministic.
// ---------------------------------------------------------------------------
__global__ __launch_bounds__(256) void combine_kernel(
    const float* __restrict__ ssim_sum, const float* __restrict__ sa_sum,
    const float* __restrict__ sbg_sum, float* __restrict__ out)
{
    __shared__ float red[4];
    const int t = threadIdx.x;
    const float invN = 1.f / 12288.f;     // 3*64*64
    float acc = 0.f;
    #pragma unroll
    for (int r = 0; r < 8; ++r) {
        const int qq = t + 256 * r;       // patch 0..2047
        const float ss = ssim_sum[3*qq] + ssim_sum[3*qq+1] + ssim_sum[3*qq+2];
        const float sa = sa_sum[3*qq]   + sa_sum[3*qq+1]   + sa_sum[3*qq+2];
        const float sb = sbg_sum[3*qq]  + sbg_sum[3*qq+1]  + sbg_sum[3*qq+2];
        const float ssim = ss * invN;
        const float diff = fminf(1.f - ssim, 1.f);     // LD = 1.0
        acc += diff * (sb * invN) + (1.f - diff) * (sa * invN);
    }
    #pragma unroll
    for (int off = 32; off; off >>= 1) acc += __shfl_down(acc, off, 64);
    if ((t & 63) == 0) red[t >> 6] = acc;
    __syncthreads();
    if (t == 0) out[0] = red[0] + red[1] + red[2] + red[3];
}

extern "C" void kernel_launch(void* const* d_in, const int* in_sizes, int n_in,
                              void* d_out, int out_size, void* d_ws, size_t ws_size,
                              hipStream_t stream) {
    const float* A  = (const float*)d_in[0];
    const float* Nn = (const float*)d_in[1];
    const float* GT = (const float*)d_in[2];
    const float* G  = (const float*)d_in[3];
    const float* BG = (const float*)d_in[4];
    float* out      = (float*)d_out;

    float* ssim_sum = (float*)d_ws;            // 6144 floats
    float* sa_sum   = ssim_sum + 6144;         // 6144 floats
    float* sbg_sum  = ssim_sum + 12288;        // 6144 floats

    ssim_fused_kernel<<<dim3(2048, 3), 256, 0, stream>>>(
        A, Nn, GT, G, BG, ssim_sum, sa_sum, sbg_sum);
    combine_kernel<<<1, 256, 0, stream>>>(ssim_sum, sa_sum, sbg_sum, out);
}